// Round 2
// baseline (368.718 us; speedup 1.0000x reference)
//
#include <hip/hip_runtime.h>

// HashRouter: h = x @ W^T + b (T x 64), cand = popcount of sign bits per
// 32-output group (<=32 so %64 is identity); i0 = c0, i1 = c1 + (c1==c0).
// Outputs (float32, concat): weights[T][2]=0.5, indices[T][2], logits[T][64]=0.
//
// R2: TOK=32 -> 512 blocks (2/CU, 2 waves/SIMD) for latency hiding; K split
// across two wave-pairs with LDS combine; XOR-swizzled LDS layout kills the
// 8-way ws bank conflict R1 had (2.5e7 conflict cycles); global loads for
// chunk n+1 prefetched into registers before chunk n's FMA loop.

constexpr int H_DIM  = 2048;
constexpr int NJ     = 64;            // hash outputs per token
constexpr int TOK    = 32;            // tokens per block
constexpr int KC     = 128;           // k-chunk staged in LDS
constexpr int NCHUNK = H_DIM / KC;    // 16
constexpr int XWORDS = TOK * KC;      // 4096 floats (16 KB)
constexpr int WWORDS = NJ * KC;       // 8192 floats (32 KB)

// Swizzled word address for element [row][k4*4 .. k4*4+3]. XOR by (row>>2)&7
// because the inner loop reads rows {g*4+i}: row>>2 == g spreads the 16 (ws)
// / 8 (xs) distinct addresses across 8 bank-quads -> 2-way max -> free.
__device__ __forceinline__ int swz(int row, int col4) {
    return row * KC + ((col4 ^ ((row >> 2) & 7)) << 2);
}

__global__ __launch_bounds__(256, 2) void hash_router_kernel(
    const float* __restrict__ x,   // [T, H]
    const float* __restrict__ w,   // [64, H]
    const float* __restrict__ b,   // [64]
    float* __restrict__ out,       // [2T | 2T | 64T]
    int T)
{
    __shared__ float smem[XWORDS + WWORDS];          // 48 KB, reused for reduce
    __shared__ unsigned int bitw[TOK][2];

    const int tid  = threadIdx.x;
    const int o    = tid & 15;          // outputs o*4 .. o*4+3
    const int tt   = (tid >> 4) & 7;    // tokens  tt*4 .. tt*4+3
    const int kg   = tid >> 7;          // K-half (0: k4 0..15, 1: k4 16..31)
    const int tok0 = blockIdx.x * TOK;

    if (tid < TOK * 2) ((unsigned int*)bitw)[tid] = 0u;

    float acc[4][4];
#pragma unroll
    for (int t = 0; t < 4; ++t)
#pragma unroll
        for (int c = 0; c < 4; ++c) acc[t][c] = 0.f;

    // Staging: 3072 float4 per chunk (x: 1024, w: 2048), 12 per thread.
    float4 pre[12];
    auto load_chunk = [&](int k0) {
#pragma unroll
        for (int it = 0; it < 4; ++it) {
            const int idx = tid + it * 256;
            const int row = idx >> 5, c4 = idx & 31;
            pre[it] = *(const float4*)(x + (size_t)(tok0 + row) * H_DIM + k0 + c4 * 4);
        }
#pragma unroll
        for (int it = 0; it < 8; ++it) {
            const int idx = tid + it * 256;
            const int row = idx >> 5, c4 = idx & 31;
            pre[4 + it] = *(const float4*)(w + (size_t)row * H_DIM + k0 + c4 * 4);
        }
    };
    auto store_chunk = [&]() {
#pragma unroll
        for (int it = 0; it < 4; ++it) {
            const int idx = tid + it * 256;
            *(float4*)(smem + swz(idx >> 5, idx & 31)) = pre[it];
        }
#pragma unroll
        for (int it = 0; it < 8; ++it) {
            const int idx = tid + it * 256;
            *(float4*)(smem + XWORDS + swz(idx >> 5, idx & 31)) = pre[4 + it];
        }
    };

    load_chunk(0);
    for (int ch = 0; ch < NCHUNK; ++ch) {
        __syncthreads();               // readers of previous chunk done
        store_chunk();
        __syncthreads();
        if (ch + 1 < NCHUNK) load_chunk((ch + 1) * KC);   // prefetch next

        const float* xsp = smem;
        const float* wsp = smem + XWORDS;
#pragma unroll 4
        for (int c = 0; c < 16; ++c) {
            const int k4 = kg * 16 + c;
            float4 xv[4], wv[4];
#pragma unroll
            for (int i = 0; i < 4; ++i) xv[i] = *(const float4*)(xsp + swz(tt * 4 + i, k4));
#pragma unroll
            for (int i = 0; i < 4; ++i) wv[i] = *(const float4*)(wsp + swz(o * 4 + i, k4));
#pragma unroll
            for (int t = 0; t < 4; ++t)
#pragma unroll
                for (int cc = 0; cc < 4; ++cc) {
                    acc[t][cc] += xv[t].x * wv[cc].x;
                    acc[t][cc] += xv[t].y * wv[cc].y;
                    acc[t][cc] += xv[t].z * wv[cc].z;
                    acc[t][cc] += xv[t].w * wv[cc].w;
                }
        }
    }

    // Combine the two K-halves: kg1 dumps partials, kg0 adds.
    __syncthreads();
    float4* red = (float4*)smem;
    if (kg) {
#pragma unroll
        for (int t = 0; t < 4; ++t)
            red[(tid - 128) * 4 + t] = make_float4(acc[t][0], acc[t][1], acc[t][2], acc[t][3]);
    }
    __syncthreads();

    if (!kg) {
        float bias[4];
#pragma unroll
        for (int c = 0; c < 4; ++c) bias[c] = b[o * 4 + c];
#pragma unroll
        for (int t = 0; t < 4; ++t) {
            const float4 r = red[tid * 4 + t];
            acc[t][0] += r.x; acc[t][1] += r.y; acc[t][2] += r.z; acc[t][3] += r.w;
        }

        // Sign extraction; |h| within fp32-noise of 0 -> exact fp64 recheck
        // (~100 dots GPU-wide, negligible).
        const float TH = 5e-5f;
#pragma unroll
        for (int t = 0; t < 4; ++t) {
            unsigned int nib = 0u;
#pragma unroll
            for (int cc = 0; cc < 4; ++cc) {
                const float v = acc[t][cc] + bias[cc];
                bool pos;
                if (__builtin_expect(fabsf(v) < TH, 0)) {
                    const float* xr = x + (size_t)(tok0 + tt * 4 + t) * H_DIM;
                    const float* wr = w + (size_t)(o * 4 + cc) * H_DIM;
                    double s = (double)bias[cc];
                    for (int k = 0; k < H_DIM; ++k)
                        s += (double)xr[k] * (double)wr[k];
                    pos = (s > 0.0);
                } else {
                    pos = (v > 0.0f);
                }
                nib |= (pos ? 1u : 0u) << cc;
            }
            // outputs o*4..o*4+3 all in 32-bit group (o>>3); position within
            // the group is irrelevant (only popcount matters)
            if (nib) atomicOr(&bitw[tt * 4 + t][o >> 3], nib << ((o & 7) * 4));
        }
    }
    __syncthreads();

    if (tid < TOK) {
        const int t  = tok0 + tid;
        const int c0 = __popc(bitw[tid][0]);
        const int c1 = __popc(bitw[tid][1]);
        const int i1 = c1 + ((c1 == c0) ? 1 : 0);
        float2 wq; wq.x = 0.5f; wq.y = 0.5f;
        *(float2*)(out + 2 * (size_t)t) = wq;
        float2 iq; iq.x = (float)c0; iq.y = (float)i1;
        *(float2*)(out + 2 * (size_t)T + 2 * (size_t)t) = iq;
    }

    // router_logits = 0 (d_out re-poisoned 0xAA before every timed launch)
    float4 z; z.x = 0.f; z.y = 0.f; z.z = 0.f; z.w = 0.f;
    float* lbase = out + 4 * (size_t)T + (size_t)tok0 * NJ;
#pragma unroll
    for (int i = tid; i < TOK * NJ / 4; i += 256)
        *(float4*)(lbase + i * 4) = z;
}

extern "C" void kernel_launch(void* const* d_in, const int* in_sizes, int n_in,
                              void* d_out, int out_size, void* d_ws, size_t ws_size,
                              hipStream_t stream) {
    const float* x = (const float*)d_in[0];
    const float* w = (const float*)d_in[1];
    const float* b = (const float*)d_in[2];
    float* out = (float*)d_out;
    const int T = in_sizes[0] / H_DIM;      // 16384
    const int grid = T / TOK;               // 512
    hash_router_kernel<<<dim3(grid), dim3(256), 0, stream>>>(x, w, b, out, T);
}

// Round 3
// 293.326 us; speedup vs baseline: 1.2570x; 1.2570x over previous
//
#include <hip/hip_runtime.h>

// HashRouter: h = x @ W^T + b (T x 64), cand = popcount of sign bits per
// 32-output group; i0 = c0, i1 = c1 + (c1==c0).
// Outputs (float32, concat): weights[T][2]=0.5, indices[T][2], logits[T][64]=0.
//
// R3: (a) staging via async global_load_lds DMA (no VGPRs -> no scratch spill,
// which cost R2 ~340 MB of HBM writes), double-buffered with ONE barrier per
// chunk so loads fly during compute; (b) 8x8 register tile (8-way K-split,
// LDS tree reduce) halves LDS traffic to 1 B/FMA (~2.15 GB total, the real
// bottleneck); (c) XOR swizzle on the global-address side keeps reads <=2-way.

constexpr int H_DIM  = 2048;
constexpr int NJ     = 64;             // hash outputs
constexpr int TOK    = 32;             // tokens per block
constexpr int KC     = 64;             // k-chunk (floats) staged per row
constexpr int NCHUNK = H_DIM / KC;     // 32
constexpr int XF     = TOK * KC;       // 2048 floats per x buffer
constexpr int WF     = NJ * KC;        // 4096 floats per w buffer
constexpr int BUF    = XF + WF;        // 6144 floats (24 KB) per buffer
constexpr int XSLOTS = XF / 4;         // 512 float4 slots (x region)

// Row swizzle for k4-column permutation. Verified by enumeration: inner-loop
// reads (rows g*8+i over og 0..7 / tg 0..3, k4 = kg*2+c) land <=2 addresses
// per bank-quad -> conflict-free (2-way is free per m136).
__device__ __forceinline__ int sw_of(int row) {
    return (3 * (row >> 3) + ((row >> 2) & 1)) & 7;
}

// Async 16B global->LDS DMA. LDS dest is wave-uniform base + lane*16 (m104),
// so LDS layout is lane-linear and the swizzle is applied to the GLOBAL column
// instead: LDS[row][c4p] holds global column (c4p ^ sw_of(row)).
__device__ __forceinline__ void stage_chunk(const float* __restrict__ x,
                                            const float* __restrict__ w,
                                            float* smem, int fb,
                                            int tok0, int k0, int tid) {
#pragma unroll
    for (int it = 0; it < 6; ++it) {
        const int slot = it * 256 + tid;           // 1536 slots: 512 x, 1024 w
        const float* g;
        if (slot < XSLOTS) {
            const int row = slot >> 4, c4p = slot & 15;
            g = x + (size_t)(tok0 + row) * H_DIM + k0 + ((c4p ^ sw_of(row)) << 2);
        } else {
            const int s2 = slot - XSLOTS;
            const int row = s2 >> 4, c4p = s2 & 15;
            g = w + (size_t)row * H_DIM + k0 + ((c4p ^ sw_of(row)) << 2);
        }
        __builtin_amdgcn_global_load_lds(
            (const __attribute__((address_space(1))) void*)g,
            (__attribute__((address_space(3))) void*)(smem + fb + slot * 4),
            16, 0, 0);
    }
}

__global__ __launch_bounds__(256, 2) void hash_router_kernel(
    const float* __restrict__ x,   // [T, H]
    const float* __restrict__ w,   // [64, H]
    const float* __restrict__ b,   // [64]
    float* __restrict__ out,       // [2T | 2T | 64T]
    int T)
{
    __shared__ float smem[2 * BUF];                 // 48 KB (also reduce area)
    __shared__ unsigned int bitw[TOK][2];

    const int tid = threadIdx.x;
    const int og  = tid & 7;          // outputs og*8 .. og*8+7
    const int tg  = (tid >> 3) & 3;   // tokens  tg*8 .. tg*8+7
    const int kg  = tid >> 5;         // K-eighth: k4 in {kg*2, kg*2+1} per chunk
    const int tok0 = blockIdx.x * TOK;

    if (tid < TOK * 2) ((unsigned int*)bitw)[tid] = 0u;

    float acc[8][8];
#pragma unroll
    for (int i = 0; i < 8; ++i)
#pragma unroll
        for (int j = 0; j < 8; ++j) acc[i][j] = 0.f;

    stage_chunk(x, w, smem, 0, tok0, 0, tid);

    for (int ch = 0; ch < NCHUNK; ++ch) {
        __builtin_amdgcn_s_waitcnt(0x0f70);   // vmcnt(0): chunk ch landed
        __syncthreads();
        if (ch + 1 < NCHUNK)                  // prefetch flies during compute
            stage_chunk(x, w, smem, ((ch + 1) & 1) * BUF, tok0, (ch + 1) * KC, tid);

        const int fb = (ch & 1) * BUF;
#pragma unroll
        for (int c = 0; c < 2; ++c) {
            const int k4 = kg * 2 + c;
            float4 xv[8];
#pragma unroll
            for (int i = 0; i < 8; ++i) {
                const int row = tg * 8 + i;
                xv[i] = *(const float4*)(smem + fb + row * KC + ((k4 ^ sw_of(row)) << 2));
            }
#pragma unroll
            for (int j = 0; j < 8; ++j) {
                const int row = og * 8 + j;
                const float4 wv = *(const float4*)(smem + fb + XF + row * KC + ((k4 ^ sw_of(row)) << 2));
#pragma unroll
                for (int i = 0; i < 8; ++i) {
                    acc[i][j] += xv[i].x * wv.x;
                    acc[i][j] += xv[i].y * wv.y;
                    acc[i][j] += xv[i].z * wv.z;
                    acc[i][j] += xv[i].w * wv.w;
                }
            }
        }
    }

    // ---- K-split tree reduce (8 -> 4 -> 2 -> 1), swizzled to avoid conflicts.
    __syncthreads();                      // buf readers done; smem reusable
    const int s  = tid & 31;              // (tg,og) slot id
    const int sw = s & 7;
#define ACC_PACK(f4) make_float4(acc[(f4) >> 1][((f4) & 1) * 4],     \
                                 acc[(f4) >> 1][((f4) & 1) * 4 + 1], \
                                 acc[(f4) >> 1][((f4) & 1) * 4 + 2], \
                                 acc[(f4) >> 1][((f4) & 1) * 4 + 3])
#define ACC_ADD(f4, v) { acc[(f4) >> 1][((f4) & 1) * 4]     += (v).x; \
                         acc[(f4) >> 1][((f4) & 1) * 4 + 1] += (v).y; \
                         acc[(f4) >> 1][((f4) & 1) * 4 + 2] += (v).z; \
                         acc[(f4) >> 1][((f4) & 1) * 4 + 3] += (v).w; }
    if (kg >= 4) {
        float* base = smem + ((kg - 4) * 32 + s) * 64;
#pragma unroll
        for (int f4 = 0; f4 < 16; ++f4) *(float4*)(base + ((f4 ^ sw) << 2)) = ACC_PACK(f4);
    }
    __syncthreads();
    if (kg < 4) {
        const float* base = smem + (kg * 32 + s) * 64;
#pragma unroll
        for (int f4 = 0; f4 < 16; ++f4) { float4 v = *(const float4*)(base + ((f4 ^ sw) << 2)); ACC_ADD(f4, v); }
    }
    __syncthreads();
    if (kg == 2 || kg == 3) {
        float* base = smem + ((kg - 2) * 32 + s) * 64;
#pragma unroll
        for (int f4 = 0; f4 < 16; ++f4) *(float4*)(base + ((f4 ^ sw) << 2)) = ACC_PACK(f4);
    }
    __syncthreads();
    if (kg < 2) {
        const float* base = smem + (kg * 32 + s) * 64;
#pragma unroll
        for (int f4 = 0; f4 < 16; ++f4) { float4 v = *(const float4*)(base + ((f4 ^ sw) << 2)); ACC_ADD(f4, v); }
    }
    __syncthreads();
    if (kg == 1) {
        float* base = smem + s * 64;
#pragma unroll
        for (int f4 = 0; f4 < 16; ++f4) *(float4*)(base + ((f4 ^ sw) << 2)) = ACC_PACK(f4);
    }
    __syncthreads();

    if (kg == 0) {
        const float* base = smem + s * 64;
#pragma unroll
        for (int f4 = 0; f4 < 16; ++f4) { float4 v = *(const float4*)(base + ((f4 ^ sw) << 2)); ACC_ADD(f4, v); }

        float bias[8];
#pragma unroll
        for (int j = 0; j < 8; ++j) bias[j] = b[og * 8 + j];

        // Sign extraction; |h| within fp32-noise of 0 -> exact fp64 recheck
        // (~100 dots GPU-wide, negligible).
        const float TH = 5e-5f;
#pragma unroll
        for (int i = 0; i < 8; ++i) {
            unsigned int byte = 0u;
#pragma unroll
            for (int j = 0; j < 8; ++j) {
                const float v = acc[i][j] + bias[j];
                bool pos;
                if (__builtin_expect(fabsf(v) < TH, 0)) {
                    const float* xr = x + (size_t)(tok0 + tg * 8 + i) * H_DIM;
                    const float* wr = w + (size_t)(og * 8 + j) * H_DIM;
                    double sd = (double)bias[j];
                    for (int k = 0; k < H_DIM; ++k)
                        sd += (double)xr[k] * (double)wr[k];
                    pos = (sd > 0.0);
                } else {
                    pos = (v > 0.0f);
                }
                byte |= (pos ? 1u : 0u) << j;
            }
            // outs og*8.. all in 32-bit group og>>2; position within group
            // is irrelevant (only popcount matters)
            if (byte) atomicOr(&bitw[tg * 8 + i][og >> 2], byte << ((og & 3) * 8));
        }
    }
    __syncthreads();

    if (tid < TOK) {
        const int t  = tok0 + tid;
        const int c0 = __popc(bitw[tid][0]);
        const int c1 = __popc(bitw[tid][1]);
        const int i1 = c1 + ((c1 == c0) ? 1 : 0);
        float2 wq; wq.x = 0.5f; wq.y = 0.5f;
        *(float2*)(out + 2 * (size_t)t) = wq;
        float2 iq; iq.x = (float)c0; iq.y = (float)i1;
        *(float2*)(out + 2 * (size_t)T + 2 * (size_t)t) = iq;
    }

    // router_logits = 0 (d_out re-poisoned 0xAA before every timed launch)
    float4 z; z.x = 0.f; z.y = 0.f; z.z = 0.f; z.w = 0.f;
    float* lbase = out + 4 * (size_t)T + (size_t)tok0 * NJ;
#pragma unroll
    for (int i = tid; i < TOK * NJ / 4; i += 256)
        *(float4*)(lbase + i * 4) = z;
}

extern "C" void kernel_launch(void* const* d_in, const int* in_sizes, int n_in,
                              void* d_out, int out_size, void* d_ws, size_t ws_size,
                              hipStream_t stream) {
    const float* x = (const float*)d_in[0];
    const float* w = (const float*)d_in[1];
    const float* b = (const float*)d_in[2];
    float* out = (float*)d_out;
    const int T = in_sizes[0] / H_DIM;      // 16384
    const int grid = T / TOK;               // 512
    hash_router_kernel<<<dim3(grid), dim3(256), 0, stream>>>(x, w, b, out, T);
}